// Round 5
// baseline (426.707 us; speedup 1.0000x reference)
//
#include <hip/hip_runtime.h>
#include <hip/hip_bf16.h>

#define QLEN 1024
#define KLEN 2560
#define MTOT 1536   // KLEN - QLEN
#define BSZ 2
#define NH 16
#define DH 64
#define DMODEL 1024
#define DINNER 4096

typedef short bf16x8 __attribute__((ext_vector_type(8)));
typedef float f32x4  __attribute__((ext_vector_type(4)));

__device__ __forceinline__ short f2bf(float f) {
    union { float f; unsigned u; } v; v.f = f;
    unsigned r = v.u + 0x7FFFu + ((v.u >> 16) & 1u);
    return (short)(r >> 16);
}
__device__ __forceinline__ float bf2f(short s) {
    union { unsigned u; float f; } v; v.u = ((unsigned)(unsigned short)s) << 16;
    return v.f;
}
__device__ __forceinline__ unsigned pack2(float a, float b) {
    return (unsigned)(unsigned short)f2bf(a) | ((unsigned)(unsigned short)f2bf(b) << 16);
}

#define GLOAD16(g, l)                                                        \
    __builtin_amdgcn_global_load_lds(                                        \
        (const __attribute__((address_space(1))) unsigned int*)(g),          \
        (__attribute__((address_space(3))) unsigned int*)(l), 16, 0, 0)

// ---------------------------------------------------------------------------
// Elementwise converters
// ---------------------------------------------------------------------------
__global__ __launch_bounds__(256) void conv_cat(
    const float* __restrict__ mem, const float* __restrict__ cmem,
    const float* __restrict__ inp, short* __restrict__ out)
{
    const int i = blockIdx.x * 256 + threadIdx.x;
    const int row = i >> 7;
    const int c = (i & 127) * 8;
    const float* src;
    if (row < 2048)      src = mem  + (size_t)row * 1024;
    else if (row < 3072) src = cmem + (size_t)(row - 2048) * 1024;
    else                 src = inp  + (size_t)(row - 3072) * 1024;
    const float4 a = *(const float4*)(src + c);
    const float4 b = *(const float4*)(src + c + 4);
    uint4 o;
    o.x = pack2(a.x, a.y); o.y = pack2(a.z, a.w);
    o.z = pack2(b.x, b.y); o.w = pack2(b.z, b.w);
    *(uint4*)(out + (size_t)i * 8) = o;
}

__global__ __launch_bounds__(256) void conv_flat(
    const float* __restrict__ in, short* __restrict__ out)
{
    const int i = blockIdx.x * 256 + threadIdx.x;
    const float4 a = *(const float4*)(in + (size_t)i * 8);
    const float4 b = *(const float4*)(in + (size_t)i * 8 + 4);
    uint4 o;
    o.x = pack2(a.x, a.y); o.y = pack2(a.z, a.w);
    o.z = pack2(b.x, b.y); o.w = pack2(b.z, b.w);
    *(uint4*)(out + (size_t)i * 8) = o;
}

// in: (K,N) f32 row-major -> out: (N,K) bf16 row-major. Grid (N/64, K/64).
__global__ __launch_bounds__(256) void transpose_conv(
    const float* __restrict__ in, short* __restrict__ out, int K, int N)
{
    __shared__ float ts[64][65];
    const int k0 = blockIdx.y * 64, n0 = blockIdx.x * 64;
    const int tid = threadIdx.x;
    const int r = tid >> 2, cb = (tid & 3) * 16;
    #pragma unroll
    for (int u = 0; u < 16; u += 4) {
        const float4 v = *(const float4*)(in + (size_t)(k0 + r) * N + n0 + cb + u);
        ts[r][cb + u] = v.x; ts[r][cb + u + 1] = v.y;
        ts[r][cb + u + 2] = v.z; ts[r][cb + u + 3] = v.w;
    }
    __syncthreads();
    #pragma unroll
    for (int p = 0; p < 4; p++) {
        const int wr_ = (tid >> 4) + p * 16;
        const int c   = (tid & 15) * 4;
        uint2 pk;
        pk.x = pack2(ts[c][wr_], ts[c + 1][wr_]);
        pk.y = pack2(ts[c + 2][wr_], ts[c + 3][wr_]);
        *(uint2*)(out + (size_t)(n0 + wr_) * K + k0 + c) = pk;
    }
}

// whb V-part (key-major) -> vtb (BSZ*NH, DH, KLEN) key-minor. Grid (40, 32).
__global__ __launch_bounds__(256) void vt_conv(
    const short* __restrict__ wh, short* __restrict__ vt)
{
    __shared__ short Ts[64][72];
    const int j0 = blockIdx.x * 64;
    const int bn = blockIdx.y;
    const int b = bn >> 4, n = bn & 15;
    const int tid = threadIdx.x;
    {
        const int key = tid >> 2, c = (tid & 3) * 16;
        const short* p = wh + ((size_t)(j0 + key) * BSZ + b) * 3072 + 2048 + n * 64 + c;
        *(bf16x8*)&Ts[key][c]     = *(const bf16x8*)p;
        *(bf16x8*)&Ts[key][c + 8] = *(const bf16x8*)(p + 8);
    }
    __syncthreads();
    {
        const int d = tid >> 2, kc = (tid & 3) * 16;
        __attribute__((aligned(16))) short tmp[16];
        #pragma unroll
        for (int u = 0; u < 16; u++) tmp[u] = Ts[kc + u][d];
        short* q = vt + ((size_t)(bn * 64) + d) * KLEN + j0 + kc;
        *(uint4*)q       = *(uint4*)tmp;
        *(uint4*)(q + 8) = *((uint4*)tmp + 1);
    }
}

// ---------------------------------------------------------------------------
// bf16 MFMA GEMM (m97 structure): C(MxN) = A(MxK) @ Bt(NxK)^T  (unchanged)
// ---------------------------------------------------------------------------
template <int EPI, int OUTBF>
__global__ __launch_bounds__(256) void gemm_bf16(
    const short* __restrict__ A, const short* __restrict__ Bt,
    const float* __restrict__ bias,
    float* __restrict__ C, short* __restrict__ Cb,
    int M, int N, int K)
{
    __shared__ short As[128 * 32];
    __shared__ short Bs[128 * 32];

    const int tid = threadIdx.x;
    const int w  = tid >> 6;
    const int l  = tid & 63;
    const int lg = l >> 4, lc = l & 15;
    const int wr = w >> 1, wc = w & 1;
    const int bm = blockIdx.y * 128, bn = blockIdx.x * 128;

    const int srow = 2 * w * 16 + (l >> 2);
    const int scol = (l & 3) * 8;
    const size_t aoff0 = (size_t)(bm + srow) * K + scol;
    const size_t boff0 = (size_t)(bn + srow) * K + scol;
    const size_t rstep = (size_t)16 * K;
    short* lA0 = As + 2 * w * 512;
    short* lA1 = As + (2 * w + 1) * 512;
    short* lB0 = Bs + 2 * w * 512;
    short* lB1 = Bs + (2 * w + 1) * 512;

    f32x4 acc[4][4];
    #pragma unroll
    for (int m = 0; m < 4; m++)
        #pragma unroll
        for (int n = 0; n < 4; n++) acc[m][n] = (f32x4){0.f, 0.f, 0.f, 0.f};

    for (int k0 = 0; k0 < K; k0 += 32) {
        GLOAD16(A + aoff0 + k0, lA0);
        GLOAD16(A + aoff0 + rstep + k0, lA1);
        GLOAD16(Bt + boff0 + k0, lB0);
        GLOAD16(Bt + boff0 + rstep + k0, lB1);
        __syncthreads();

        bf16x8 af[4], bfr[4];
        #pragma unroll
        for (int m = 0; m < 4; m++)
            af[m] = *(const bf16x8*)(As + (wr * 64 + m * 16 + lc) * 32 + lg * 8);
        #pragma unroll
        for (int n = 0; n < 4; n++)
            bfr[n] = *(const bf16x8*)(Bs + (wc * 64 + n * 16 + lc) * 32 + lg * 8);
        #pragma unroll
        for (int m = 0; m < 4; m++)
            #pragma unroll
            for (int n = 0; n < 4; n++)
                acc[m][n] = __builtin_amdgcn_mfma_f32_16x16x32_bf16(
                    af[m], bfr[n], acc[m][n], 0, 0, 0);
        __syncthreads();
    }

    #pragma unroll
    for (int m = 0; m < 4; m++) {
        #pragma unroll
        for (int n = 0; n < 4; n++) {
            const int col = bn + wc * 64 + n * 16 + lc;
            const float bv = (EPI >= 1) ? bias[col] : 0.0f;
            #pragma unroll
            for (int r = 0; r < 4; r++) {
                const int row = bm + wr * 64 + m * 16 + lg * 4 + r;
                float v = acc[m][n][r] + bv;
                if (EPI == 1) v = fmaxf(v, 0.0f);
                if (OUTBF) Cb[(size_t)row * N + col] = f2bf(v);
                else       C [(size_t)row * N + col] = v;
            }
        }
    }
}

// ---------------------------------------------------------------------------
// MFMA flash attention, 2-way split-K, XOR-swizzled LDS.
// Grid (16, 32, 2); block 256 = 4 waves, wave w owns 16 q-rows.
// z=0 covers [0, jhalf) (provably unmasked), z=1 covers [jhalf, jend).
// Emits unnormalized partial O (bf16) + per-row (m, l) for the merge kernel.
// LDS rows are 64 shorts (128 B); 16B-chunk index c is swizzled c ^= (row&7).
// ---------------------------------------------------------------------------
__global__ __launch_bounds__(256) void attn_mfma(
    const short* __restrict__ wh,   // (KLEN*BSZ, 3072) bf16
    const short* __restrict__ vt,   // (BSZ*NH, DH, KLEN) bf16
    const short* __restrict__ rk,   // (KLEN, NH*DH) bf16
    const float* __restrict__ rwb,
    const float* __restrict__ rrb,
    short* __restrict__ po,         // (2, 512, 64, 64) bf16
    float* __restrict__ ml)         // (2, 512, 64, 2) f32
{
    __shared__ __align__(16) short Ks[64 * 64];
    __shared__ __align__(16) short Vs[64 * 64];    // [d][key]
    __shared__ __align__(16) short Rs[128 * 64];
    __shared__ __align__(16) short Ps[4][16 * 64];

    const int ib  = blockIdx.x;
    const int i0  = ib * 64;
    const int bn  = blockIdx.y;
    const int b   = bn >> 4, n = bn & 15;
    const int z   = blockIdx.z;
    const int tid = threadIdx.x;
    const int w   = tid >> 6;
    const int l   = tid & 63;
    const int lg  = l >> 4;
    const int lc  = l & 15;
    const int i_base = i0 + 16 * w;

    bf16x8 aqw[2], aqr[2];
    {
        const int i = i_base + lc;
        const short* qp = wh + ((size_t)(MTOT + i) * BSZ + b) * 3072 + n * 64;
        #pragma unroll
        for (int kc = 0; kc < 2; kc++) {
            const bf16x8 q8 = *(const bf16x8*)(qp + kc * 32 + lg * 8);
            const int d0 = kc * 32 + lg * 8;
            #pragma unroll
            for (int e = 0; e < 8; e++) {
                const float qv = bf2f(q8[e]);
                aqw[kc][e] = f2bf(qv + rwb[n * 64 + d0 + e]);
                aqr[kc][e] = f2bf(qv + rrb[n * 64 + d0 + e]);
            }
        }
    }

    f32x4 o_acc[4];
    #pragma unroll
    for (int nt = 0; nt < 4; nt++) o_acc[nt] = (f32x4){0.f, 0.f, 0.f, 0.f};
    float mrun[4] = {-1e30f, -1e30f, -1e30f, -1e30f};
    float lrun[4] = {0.f, 0.f, 0.f, 0.f};

    const int jend   = i0 + 1600;
    const int jhalf  = (((jend >> 1) + 63) >> 6) << 6;
    const int jstart = z ? jhalf : 0;
    const int jstop  = z ? jend  : jhalf;

    for (int j0 = jstart; j0 < jstop; j0 += 64) {
        __syncthreads();
        // ---- stage K and V^T (vector writes, swizzled) ----
        #pragma unroll
        for (int u = 0; u < 2; u++) {
            const int ci  = tid * 2 + u;
            const int row = ci >> 3, c = ci & 7;
            const int sw  = (c ^ (row & 7)) * 8;
            const bf16x8 kv = *(const bf16x8*)(
                wh + ((size_t)(j0 + row) * BSZ + b) * 3072 + 1024 + n * 64 + c * 8);
            *(bf16x8*)(Ks + row * 64 + sw) = kv;
            const bf16x8 vv = *(const bf16x8*)(
                vt + ((size_t)(bn * 64) + row) * KLEN + j0 + c * 8);
            *(bf16x8*)(Vs + row * 64 + sw) = vv;
        }
        // ---- stage R window (128 rows) ----
        {
            const int mbase = j0 - i0 + 960;
            #pragma unroll
            for (int u = 0; u < 4; u++) {
                const int ci  = tid + 256 * u;
                const int row = ci >> 3, c = ci & 7;
                const int m   = mbase + row;
                bf16x8 rv = (bf16x8){0, 0, 0, 0, 0, 0, 0, 0};
                if (m < KLEN)
                    rv = *(const bf16x8*)(rk + (size_t)m * 1024 + n * 64 + c * 8);
                *(bf16x8*)(Rs + row * 64 + ((c ^ (row & 7)) * 8)) = rv;
            }
        }
        __syncthreads();

        // ---- AC = (Q+rwb) @ K^T ----
        f32x4 sfr[4];
        #pragma unroll
        for (int jt = 0; jt < 4; jt++) {
            const int row = 16 * jt + lc;
            const int c0 = (lg ^ (row & 7)) * 8, c1 = ((4 + lg) ^ (row & 7)) * 8;
            const bf16x8 bk0 = *(const bf16x8*)(Ks + row * 64 + c0);
            const bf16x8 bk1 = *(const bf16x8*)(Ks + row * 64 + c1);
            f32x4 acc = (f32x4){0.f, 0.f, 0.f, 0.f};
            acc = __builtin_amdgcn_mfma_f32_16x16x32_bf16(aqw[0], bk0, acc, 0, 0, 0);
            acc = __builtin_amdgcn_mfma_f32_16x16x32_bf16(aqw[1], bk1, acc, 0, 0, 0);
            sfr[jt] = acc;
        }
        // ---- Dr = (Q+rrb) @ R^T (80 shift positions) ----
        f32x4 dr[5];
        #pragma unroll
        for (int mt = 0; mt < 5; mt++) {
            const int rrow = 16 * mt + lc + 48 - 16 * w;
            const int c0 = (lg ^ (rrow & 7)) * 8, c1 = ((4 + lg) ^ (rrow & 7)) * 8;
            const bf16x8 br0 = *(const bf16x8*)(Rs + rrow * 64 + c0);
            const bf16x8 br1 = *(const bf16x8*)(Rs + rrow * 64 + c1);
            f32x4 acc = (f32x4){0.f, 0.f, 0.f, 0.f};
            acc = __builtin_amdgcn_mfma_f32_16x16x32_bf16(aqr[0], br0, acc, 0, 0, 0);
            acc = __builtin_amdgcn_mfma_f32_16x16x32_bf16(aqr[1], br1, acc, 0, 0, 0);
            dr[mt] = acc;
        }

        // ---- rel-shift gather + online softmax ----
        #pragma unroll
        for (int r = 0; r < 4; r++) {
            const int q   = 4 * lg + r;
            const int o   = lc + 15 - q;
            const int src = (l & 48) | (o & 15);
            float sv[4];
            float mx = -1e30f;
            #pragma unroll
            for (int jt = 0; jt < 4; jt++) {
                const float v0 = __shfl(dr[jt][r], src);
                const float v1 = __shfl(dr[jt + 1][r], src);
                const float bd = (o < 16) ? v0 : v1;
                float s = (sfr[jt][r] + bd) * 0.125f;
                if (z) {
                    const int j = j0 + 16 * jt + lc;
                    if (j > i_base + q + MTOT) s = -1e30f;
                }
                sv[jt] = s;
                mx = fmaxf(mx, s);
            }
            #pragma unroll
            for (int msk = 1; msk <= 8; msk <<= 1)
                mx = fmaxf(mx, __shfl_xor(mx, msk));
            const float mnew = fmaxf(mrun[r], mx);
            const float corr = __expf(mrun[r] - mnew);
            mrun[r] = mnew;
            float ps = 0.f;
            #pragma unroll
            for (int jt = 0; jt < 4; jt++) {
                const float p = __expf(sv[jt] - mnew);
                ps += p;
                // swizzled b16 write: row q, col 16*jt+lc
                Ps[w][q * 64 + (((2 * jt + (lc >> 3)) ^ (q & 7)) * 8) + (lc & 7)] = f2bf(p);
            }
            #pragma unroll
            for (int msk = 1; msk <= 8; msk <<= 1)
                ps += __shfl_xor(ps, msk);
            lrun[r] = lrun[r] * corr + ps;
            #pragma unroll
            for (int nt = 0; nt < 4; nt++) o_acc[nt][r] *= corr;
        }

        asm volatile("s_waitcnt lgkmcnt(0)" ::: "memory");
        __builtin_amdgcn_sched_barrier(0);

        // ---- O += P @ V ----
        const int pc0 = (lg ^ (lc & 7)) * 8, pc1 = ((4 + lg) ^ (lc & 7)) * 8;
        const bf16x8 pa0 = *(const bf16x8*)(Ps[w] + lc * 64 + pc0);
        const bf16x8 pa1 = *(const bf16x8*)(Ps[w] + lc * 64 + pc1);
        #pragma unroll
        for (int nt = 0; nt < 4; nt++) {
            const int row = 16 * nt + lc;
            const int c0 = (lg ^ (row & 7)) * 8, c1 = ((4 + lg) ^ (row & 7)) * 8;
            const bf16x8 bv0 = *(const bf16x8*)(Vs + row * 64 + c0);
            const bf16x8 bv1 = *(const bf16x8*)(Vs + row * 64 + c1);
            o_acc[nt] = __builtin_amdgcn_mfma_f32_16x16x32_bf16(pa0, bv0, o_acc[nt], 0, 0, 0);
            o_acc[nt] = __builtin_amdgcn_mfma_f32_16x16x32_bf16(pa1, bv1, o_acc[nt], 0, 0, 0);
        }
    }

    // ---- epilogue: write unnormalized partials ----
    // BUGFIX vs round 4: row index must include the wave offset 16*w.
    const size_t blk = (size_t)z * 512 + ib * 32 + bn;
    #pragma unroll
    for (int r = 0; r < 4; r++) {
        const int q = 16 * w + 4 * lg + r;
        #pragma unroll
        for (int nt = 0; nt < 4; nt++)
            po[(blk * 64 + q) * 64 + 16 * nt + lc] = f2bf(o_acc[nt][r]);
        if (lc == 0) {
            ml[(blk * 64 + q) * 2 + 0] = mrun[r];
            ml[(blk * 64 + q) * 2 + 1] = lrun[r];
        }
    }
}

// ---------------------------------------------------------------------------
// Merge the two split-K partials -> attn_vec (bf16). Grid (512), 256 thr.
// ---------------------------------------------------------------------------
__global__ __launch_bounds__(256) void attn_merge(
    const short* __restrict__ po, const float* __restrict__ ml,
    short* __restrict__ av)
{
    const int blk = blockIdx.x;
    const int ib = blk >> 5, bn = blk & 31;
    const int b = bn >> 4, n = bn & 15;
    const int tid = threadIdx.x;
    const int q = tid >> 2, dc = (tid & 3) * 16;
    const size_t r0 = (size_t)blk * 64 + q;
    const size_t r1 = (size_t)(512 + blk) * 64 + q;
    const float m0 = ml[r0 * 2], l0 = ml[r0 * 2 + 1];
    const float m1 = ml[r1 * 2], l1 = ml[r1 * 2 + 1];
    const float M = fmaxf(m0, m1);
    const float c0 = __expf(m0 - M), c1 = __expf(m1 - M);
    const float invL = 1.0f / (l0 * c0 + l1 * c1);
    const bf16x8 a0 = *(const bf16x8*)(po + r0 * 64 + dc);
    const bf16x8 a1 = *(const bf16x8*)(po + r0 * 64 + dc + 8);
    const bf16x8 b0 = *(const bf16x8*)(po + r1 * 64 + dc);
    const bf16x8 b1 = *(const bf16x8*)(po + r1 * 64 + dc + 8);
    __attribute__((aligned(16))) short ov[16];
    #pragma unroll
    for (int e = 0; e < 8; e++) {
        ov[e]     = f2bf((bf2f(a0[e]) * c0 + bf2f(b0[e]) * c1) * invL);
        ov[e + 8] = f2bf((bf2f(a1[e]) * c0 + bf2f(b1[e]) * c1) * invL);
    }
    const int i = ib * 64 + q;
    short* op = av + ((size_t)i * BSZ + b) * 1024 + n * 64 + dc;
    *(uint4*)op       = *(uint4*)ov;
    *(uint4*)(op + 8) = *((uint4*)ov + 1);
}

// ---------------------------------------------------------------------------
// LayerNorm with residual add; optional bf16 aux output. (unchanged)
// ---------------------------------------------------------------------------
template <bool WB>
__global__ __launch_bounds__(256) void ln_kernel(
    const float* __restrict__ x, const float* __restrict__ res,
    const float* __restrict__ scale, const float* __restrict__ bias,
    float* __restrict__ out, short* __restrict__ outb)
{
    const int row = blockIdx.x;
    const int tid = threadIdx.x;
    const size_t base = (size_t)row * 1024 + tid * 4;
    const float4 xv = *(const float4*)(x + base);
    const float4 rv = *(const float4*)(res + base);
    float v[4] = {xv.x + rv.x, xv.y + rv.y, xv.z + rv.z, xv.w + rv.w};
    float s  = v[0] + v[1] + v[2] + v[3];
    float ss = v[0]*v[0] + v[1]*v[1] + v[2]*v[2] + v[3]*v[3];
    #pragma unroll
    for (int off = 32; off >= 1; off >>= 1) {
        s  += __shfl_down(s, off);
        ss += __shfl_down(ss, off);
    }
    __shared__ float red[8];
    const int lane = tid & 63, wid = tid >> 6;
    if (lane == 0) { red[wid] = s; red[4 + wid] = ss; }
    __syncthreads();
    if (tid == 0) {
        red[0] = red[0] + red[1] + red[2] + red[3];
        red[4] = red[4] + red[5] + red[6] + red[7];
    }
    __syncthreads();
    const float mean = red[0] * (1.0f / 1024.0f);
    const float var  = red[4] * (1.0f / 1024.0f) - mean * mean;
    const float rstd = rsqrtf(var + 1e-5f);
    const float4 sc = *(const float4*)(scale + tid * 4);
    const float4 bi = *(const float4*)(bias + tid * 4);
    float4 o;
    o.x = (v[0] - mean) * rstd * sc.x + bi.x;
    o.y = (v[1] - mean) * rstd * sc.y + bi.y;
    o.z = (v[2] - mean) * rstd * sc.z + bi.z;
    o.w = (v[3] - mean) * rstd * sc.w + bi.w;
    *(float4*)(out + base) = o;
    if (WB) {
        uint2 pk;
        pk.x = pack2(o.x, o.y);
        pk.y = pack2(o.z, o.w);
        *(uint2*)(outb + base) = pk;
    }
}

// ---------------------------------------------------------------------------
extern "C" void kernel_launch(void* const* d_in, const int* in_sizes, int n_in,
                              void* d_out, int out_size, void* d_ws, size_t ws_size,
                              hipStream_t stream) {
    const float* input_ids = (const float*)d_in[0];
    const float* pos_emb   = (const float*)d_in[1];
    const float* mem       = (const float*)d_in[2];
    const float* c_mem     = (const float*)d_in[3];
    const float* qkv_w     = (const float*)d_in[5];
    const float* r_w       = (const float*)d_in[6];
    const float* o_w       = (const float*)d_in[7];
    const float* r_w_bias  = (const float*)d_in[8];
    const float* r_r_bias  = (const float*)d_in[9];
    const float* ln_a_s    = (const float*)d_in[10];
    const float* ln_a_b    = (const float*)d_in[11];
    const float* ff_w1     = (const float*)d_in[12];
    const float* ff_b1     = (const float*)d_in[13];
    const float* ff_w2     = (const float*)d_in[14];
    const float* ff_b2     = (const float*)d_in[15];
    const float* ln_f_s    = (const float*)d_in[16];
    const float* ln_f_b    = (const float*)d_in[17];

    char* base = (char*)d_ws;
    // persistent weights
    short* o_wt   = (short*)(base + 0);          // 1024x1024      [-> GEMM5]
    short* ff1t   = (short*)(base + 2097152);    // 4096x1024      [-> GEMM7]
    short* ff2t   = (short*)(base + 10485760);   // 1024x4096      [-> GEMM8]
    // phase 1
    short* whb    = (short*)(base + 18874368);   // 5120x3072      [-> attn]
    short* rkb    = (short*)(base + 50331648);   // 2560x1024      [-> attn]
    short* qkv_wt = (short*)(base + 55574528);   // 3072x1024      [dead after G1]
    short* catb   = (short*)(base + 61865984);   // 5120x1024      [dead after G1]
    short* posb   = (short*)(base + 72351744);   // 2560x1024      [dead after G2]
    short* r_wt   = (short*)(base + 77594624);   // 1024x1024      [dead after G2]
    // phase 2 overlays (over dead G1/G2 inputs)
    short* vtb    = (short*)(base + 55574528);   // 2x16x64x2560
    short* po     = (short*)(base + 66060288);   // 2x512x64x64
    float* mlb    = (float*)(base + 74448896);   // 2x512x64x2
    short* avb    = (short*)(base + 74973184);   // 2048x1024
    // phase 3 overlays (over dead whb/rkb/vtb/po)
    float* ao     = (float*)(base + 18874368);   // 2048x1024 f32
    float* ares   = (float*)(base + 27262976);   // 2048x1024 f32
    short* aresb  = (short*)(base + 35651584);   // 2048x1024
    short* h1b    = (short*)(base + 39845888);   // 2048x4096
    float* h2     = (float*)(base + 56623104);   // 2048x1024 f32

    const dim3 thr(256);

    conv_cat<<<dim3(2560), thr, 0, stream>>>(mem, c_mem, input_ids, catb);
    conv_flat<<<dim3(1280), thr, 0, stream>>>(pos_emb, posb);
    transpose_conv<<<dim3(48, 16), thr, 0, stream>>>(qkv_w, qkv_wt, 1024, 3072);
    transpose_conv<<<dim3(16, 16), thr, 0, stream>>>(r_w,   r_wt,   1024, 1024);
    transpose_conv<<<dim3(16, 16), thr, 0, stream>>>(o_w,   o_wt,   1024, 1024);
    transpose_conv<<<dim3(64, 16), thr, 0, stream>>>(ff_w1, ff1t,   1024, 4096);
    transpose_conv<<<dim3(16, 64), thr, 0, stream>>>(ff_w2, ff2t,   4096, 1024);

    // 1) w_heads
    gemm_bf16<0, 1><<<dim3(24, 40), thr, 0, stream>>>(
        catb, qkv_wt, nullptr, nullptr, whb, 5120, 3072, 1024);
    // 2) r_k
    gemm_bf16<0, 1><<<dim3(8, 20), thr, 0, stream>>>(
        posb, r_wt, nullptr, nullptr, rkb, 2560, 1024, 1024);
    // 3) V^T materialization
    vt_conv<<<dim3(40, 32), thr, 0, stream>>>(whb, vtb);
    // 4) split-K flash attention + merge
    attn_mfma<<<dim3(16, 32, 2), thr, 0, stream>>>(
        whb, vtb, rkb, r_w_bias, r_r_bias, po, mlb);
    attn_merge<<<dim3(512), thr, 0, stream>>>(po, mlb, avb);
    // 5) attn_out
    gemm_bf16<0, 0><<<dim3(8, 16), thr, 0, stream>>>(
        avb, o_wt, nullptr, ao, nullptr, 2048, 1024, 1024);
    // 6) attn_res = LN(input + attn_out)
    ln_kernel<true><<<dim3(2048), thr, 0, stream>>>(ao, input_ids, ln_a_s, ln_a_b, ares, aresb);
    // 7) h1 = relu(ares @ ff_w1 + b1)
    gemm_bf16<1, 1><<<dim3(32, 16), thr, 0, stream>>>(
        aresb, ff1t, ff_b1, nullptr, h1b, 2048, 4096, 1024);
    // 8) h2 = h1 @ ff_w2 + b2
    gemm_bf16<2, 0><<<dim3(8, 16), thr, 0, stream>>>(
        h1b, ff2t, ff_b2, h2, nullptr, 2048, 1024, 4096);
    // 9) out = LN(ares + h2)
    ln_kernel<false><<<dim3(2048), thr, 0, stream>>>(h2, ares, ln_f_s, ln_f_b, (float*)d_out, nullptr);
}

// Round 6
// 322.748 us; speedup vs baseline: 1.3221x; 1.3221x over previous
//
#include <hip/hip_runtime.h>
#include <hip/hip_bf16.h>

#define QLEN 1024
#define KLEN 2560
#define MTOT 1536   // KLEN - QLEN
#define BSZ 2
#define NH 16
#define DH 64
#define DMODEL 1024
#define DINNER 4096

typedef short bf16x8 __attribute__((ext_vector_type(8)));
typedef float f32x4  __attribute__((ext_vector_type(4)));

__device__ __forceinline__ short f2bf(float f) {
    union { float f; unsigned u; } v; v.f = f;
    unsigned r = v.u + 0x7FFFu + ((v.u >> 16) & 1u);
    return (short)(r >> 16);
}
__device__ __forceinline__ float bf2f(short s) {
    union { unsigned u; float f; } v; v.u = ((unsigned)(unsigned short)s) << 16;
    return v.f;
}
__device__ __forceinline__ unsigned pack2(float a, float b) {
    return (unsigned)(unsigned short)f2bf(a) | ((unsigned)(unsigned short)f2bf(b) << 16);
}

#define GLOAD16(g, l)                                                        \
    __builtin_amdgcn_global_load_lds(                                        \
        (const __attribute__((address_space(1))) unsigned int*)(g),          \
        (__attribute__((address_space(3))) unsigned int*)(l), 16, 0, 0)

// ---------------------------------------------------------------------------
// prep_all: all input conversions/transposes in ONE launch (range dispatch).
//   [0,2560)    conv_cat  : [mem|c_mem|input] -> catb bf16
//   [2560,3840) conv_flat : pos_emb -> posb bf16
//   [3840,4608) transpose qkv_w (1024x3072) -> qkv_wt (3072x1024)
//   [4608,4864) transpose r_w   -> r_wt
//   [4864,5120) transpose o_w   -> o_wt
//   [5120,6144) transpose ff_w1 (1024x4096) -> ff1t (4096x1024)
//   [6144,7168) transpose ff_w2 (4096x1024) -> ff2t (1024x4096)
// ---------------------------------------------------------------------------
__device__ __forceinline__ void tr_body(
    const float* __restrict__ in, short* __restrict__ out,
    int K, int N, int bx, int by, int tid, float (*ts)[65])
{
    const int k0 = by * 64, n0 = bx * 64;
    const int r = tid >> 2, cb = (tid & 3) * 16;
    #pragma unroll
    for (int u = 0; u < 16; u += 4) {
        const float4 v = *(const float4*)(in + (size_t)(k0 + r) * N + n0 + cb + u);
        ts[r][cb + u] = v.x; ts[r][cb + u + 1] = v.y;
        ts[r][cb + u + 2] = v.z; ts[r][cb + u + 3] = v.w;
    }
    __syncthreads();
    #pragma unroll
    for (int p = 0; p < 4; p++) {
        const int wr_ = (tid >> 4) + p * 16;
        const int c   = (tid & 15) * 4;
        uint2 pk;
        pk.x = pack2(ts[c][wr_], ts[c + 1][wr_]);
        pk.y = pack2(ts[c + 2][wr_], ts[c + 3][wr_]);
        *(uint2*)(out + (size_t)(n0 + wr_) * K + k0 + c) = pk;
    }
}

__global__ __launch_bounds__(256) void prep_all(
    const float* __restrict__ mem, const float* __restrict__ cmem,
    const float* __restrict__ inp, short* __restrict__ catb,
    const float* __restrict__ pos, short* __restrict__ posb,
    const float* __restrict__ qkv_w, short* __restrict__ qkv_wt,
    const float* __restrict__ r_w, short* __restrict__ r_wt,
    const float* __restrict__ o_w, short* __restrict__ o_wt,
    const float* __restrict__ ff_w1, short* __restrict__ ff1t,
    const float* __restrict__ ff_w2, short* __restrict__ ff2t)
{
    __shared__ float ts[64][65];
    const int bid = blockIdx.x;
    const int tid = threadIdx.x;
    if (bid < 2560) {
        const int i = bid * 256 + tid;
        const int row = i >> 7, c = (i & 127) * 8;
        const float* src;
        if (row < 2048)      src = mem  + (size_t)row * 1024;
        else if (row < 3072) src = cmem + (size_t)(row - 2048) * 1024;
        else                 src = inp  + (size_t)(row - 3072) * 1024;
        const float4 a = *(const float4*)(src + c);
        const float4 b = *(const float4*)(src + c + 4);
        uint4 o;
        o.x = pack2(a.x, a.y); o.y = pack2(a.z, a.w);
        o.z = pack2(b.x, b.y); o.w = pack2(b.z, b.w);
        *(uint4*)(catb + (size_t)i * 8) = o;
    } else if (bid < 3840) {
        const int i = (bid - 2560) * 256 + tid;
        const float4 a = *(const float4*)(pos + (size_t)i * 8);
        const float4 b = *(const float4*)(pos + (size_t)i * 8 + 4);
        uint4 o;
        o.x = pack2(a.x, a.y); o.y = pack2(a.z, a.w);
        o.z = pack2(b.x, b.y); o.w = pack2(b.z, b.w);
        *(uint4*)(posb + (size_t)i * 8) = o;
    } else if (bid < 4608) {
        const int r = bid - 3840; tr_body(qkv_w, qkv_wt, 1024, 3072, r % 48, r / 48, tid, ts);
    } else if (bid < 4864) {
        const int r = bid - 4608; tr_body(r_w, r_wt, 1024, 1024, r % 16, r / 16, tid, ts);
    } else if (bid < 5120) {
        const int r = bid - 4864; tr_body(o_w, o_wt, 1024, 1024, r % 16, r / 16, tid, ts);
    } else if (bid < 6144) {
        const int r = bid - 5120; tr_body(ff_w1, ff1t, 1024, 4096, r % 64, r / 64, tid, ts);
    } else {
        const int r = bid - 6144; tr_body(ff_w2, ff2t, 4096, 1024, r % 16, r / 16, tid, ts);
    }
}

// whb V-part (key-major) -> vtb (BSZ*NH, DH, KLEN) key-minor. Grid (40, 32).
__global__ __launch_bounds__(256) void vt_conv(
    const short* __restrict__ wh, short* __restrict__ vt)
{
    __shared__ short Ts[64][72];
    const int j0 = blockIdx.x * 64;
    const int bn = blockIdx.y;
    const int b = bn >> 4, n = bn & 15;
    const int tid = threadIdx.x;
    {
        const int key = tid >> 2, c = (tid & 3) * 16;
        const short* p = wh + ((size_t)(j0 + key) * BSZ + b) * 3072 + 2048 + n * 64 + c;
        *(bf16x8*)&Ts[key][c]     = *(const bf16x8*)p;
        *(bf16x8*)&Ts[key][c + 8] = *(const bf16x8*)(p + 8);
    }
    __syncthreads();
    {
        const int d = tid >> 2, kc = (tid & 3) * 16;
        __attribute__((aligned(16))) short tmp[16];
        #pragma unroll
        for (int u = 0; u < 16; u++) tmp[u] = Ts[kc + u][d];
        short* q = vt + ((size_t)(bn * 64) + d) * KLEN + j0 + kc;
        *(uint4*)q       = *(uint4*)tmp;
        *(uint4*)(q + 8) = *((uint4*)tmp + 1);
    }
}

// ---------------------------------------------------------------------------
// Shared m97 GEMM core: 128x128 tile, BK=32, 4 waves, global_load_lds staging.
// ---------------------------------------------------------------------------
__device__ __forceinline__ void gemm_core(
    const short* __restrict__ A, const short* __restrict__ Bt,
    short* As, short* Bs, int Kfull, int klen, int bm, int bn,
    int tid, f32x4 acc[4][4])
{
    const int w  = tid >> 6;
    const int l  = tid & 63;
    const int lg = l >> 4, lc = l & 15;
    const int wr = w >> 1, wc = w & 1;
    const int srow = 2 * w * 16 + (l >> 2);
    const int scol = (l & 3) * 8;
    const size_t aoff0 = (size_t)(bm + srow) * Kfull + scol;
    const size_t boff0 = (size_t)(bn + srow) * Kfull + scol;
    const size_t rstep = (size_t)16 * Kfull;
    short* lA0 = As + 2 * w * 512;
    short* lA1 = As + (2 * w + 1) * 512;
    short* lB0 = Bs + 2 * w * 512;
    short* lB1 = Bs + (2 * w + 1) * 512;

    for (int k0 = 0; k0 < klen; k0 += 32) {
        GLOAD16(A + aoff0 + k0, lA0);
        GLOAD16(A + aoff0 + rstep + k0, lA1);
        GLOAD16(Bt + boff0 + k0, lB0);
        GLOAD16(Bt + boff0 + rstep + k0, lB1);
        __syncthreads();
        bf16x8 af[4], bfr[4];
        #pragma unroll
        for (int m = 0; m < 4; m++)
            af[m] = *(const bf16x8*)(As + (wr * 64 + m * 16 + lc) * 32 + lg * 8);
        #pragma unroll
        for (int n = 0; n < 4; n++)
            bfr[n] = *(const bf16x8*)(Bs + (wc * 64 + n * 16 + lc) * 32 + lg * 8);
        #pragma unroll
        for (int m = 0; m < 4; m++)
            #pragma unroll
            for (int n = 0; n < 4; n++)
                acc[m][n] = __builtin_amdgcn_mfma_f32_16x16x32_bf16(
                    af[m], bfr[n], acc[m][n], 0, 0, 0);
        __syncthreads();
    }
}

// G1 (w_heads) + G2 (r_k) in one launch: blocks [0,960) G1, [960,1120) G2.
__global__ __launch_bounds__(256) void gemm_g12(
    const short* __restrict__ catb, const short* __restrict__ qkv_wt,
    short* __restrict__ whb,
    const short* __restrict__ posb, const short* __restrict__ r_wt,
    short* __restrict__ rkb)
{
    __shared__ short As[4096], Bs[4096];
    const int tid = threadIdx.x;
    int id = blockIdx.x;
    const short *A, *Bt; short* Cb; int N, bm, bn;
    if (id < 960) { A = catb; Bt = qkv_wt; Cb = whb; N = 3072;
                    bm = (id / 24) * 128; bn = (id % 24) * 128; }
    else { id -= 960; A = posb; Bt = r_wt; Cb = rkb; N = 1024;
           bm = (id / 8) * 128; bn = (id % 8) * 128; }

    f32x4 acc[4][4];
    #pragma unroll
    for (int m = 0; m < 4; m++)
        #pragma unroll
        for (int n = 0; n < 4; n++) acc[m][n] = (f32x4){0.f, 0.f, 0.f, 0.f};
    gemm_core(A, Bt, As, Bs, 1024, 1024, bm, bn, tid, acc);

    const int w = tid >> 6, l = tid & 63, lg = l >> 4, lc = l & 15;
    const int wr = w >> 1, wc = w & 1;
    #pragma unroll
    for (int m = 0; m < 4; m++)
        #pragma unroll
        for (int n = 0; n < 4; n++) {
            const int col = bn + wc * 64 + n * 16 + lc;
            #pragma unroll
            for (int r = 0; r < 4; r++) {
                const int row = bm + wr * 64 + m * 16 + lg * 4 + r;
                Cb[(size_t)row * N + col] = f2bf(acc[m][n][r]);
            }
        }
}

// G7: h1 = relu(ares @ ff_w1 + b1), bf16 out. Grid (N/128, M/128).
__global__ __launch_bounds__(256) void gemm_relu(
    const short* __restrict__ A, const short* __restrict__ Bt,
    const float* __restrict__ bias, short* __restrict__ Cb,
    int N, int K)
{
    __shared__ short As[4096], Bs[4096];
    const int tid = threadIdx.x;
    const int bm = blockIdx.y * 128, bn = blockIdx.x * 128;
    f32x4 acc[4][4];
    #pragma unroll
    for (int m = 0; m < 4; m++)
        #pragma unroll
        for (int n = 0; n < 4; n++) acc[m][n] = (f32x4){0.f, 0.f, 0.f, 0.f};
    gemm_core(A, Bt, As, Bs, K, K, bm, bn, tid, acc);

    const int w = tid >> 6, l = tid & 63, lg = l >> 4, lc = l & 15;
    const int wr = w >> 1, wc = w & 1;
    #pragma unroll
    for (int m = 0; m < 4; m++)
        #pragma unroll
        for (int n = 0; n < 4; n++) {
            const int col = bn + wc * 64 + n * 16 + lc;
            const float bv = bias[col];
            #pragma unroll
            for (int r = 0; r < 4; r++) {
                const int row = bm + wr * 64 + m * 16 + lg * 4 + r;
                Cb[(size_t)row * N + col] = f2bf(fmaxf(acc[m][n][r] + bv, 0.0f));
            }
        }
}

// Split-K GEMM partial: z in {0,1} computes K-range [z*Ksub, (z+1)*Ksub),
// writing f32 partial to C0/C1. Grid (N/128, M/128, 2).
__global__ __launch_bounds__(256) void gemm_split(
    const short* __restrict__ A, const short* __restrict__ Bt,
    float* __restrict__ C0, float* __restrict__ C1,
    int N, int Kfull, int Ksub)
{
    __shared__ short As[4096], Bs[4096];
    const int tid = threadIdx.x;
    const int z = blockIdx.z;
    const int bm = blockIdx.y * 128, bn = blockIdx.x * 128;
    float* C = z ? C1 : C0;
    f32x4 acc[4][4];
    #pragma unroll
    for (int m = 0; m < 4; m++)
        #pragma unroll
        for (int n = 0; n < 4; n++) acc[m][n] = (f32x4){0.f, 0.f, 0.f, 0.f};
    gemm_core(A + z * Ksub, Bt + z * Ksub, As, Bs, Kfull, Ksub, bm, bn, tid, acc);

    const int w = tid >> 6, l = tid & 63, lg = l >> 4, lc = l & 15;
    const int wr = w >> 1, wc = w & 1;
    #pragma unroll
    for (int m = 0; m < 4; m++)
        #pragma unroll
        for (int n = 0; n < 4; n++) {
            const int col = bn + wc * 64 + n * 16 + lc;
            #pragma unroll
            for (int r = 0; r < 4; r++) {
                const int row = bm + wr * 64 + m * 16 + lg * 4 + r;
                C[(size_t)row * N + col] = acc[m][n][r];
            }
        }
}

// ---------------------------------------------------------------------------
// MFMA flash attention, 2-way split-K, XOR-swizzled LDS, DEFER-MAX softmax.
// m starts at 0; rescale only if __any(row-max - m > 8) (T13). Per-lane
// partial l accumulates; single shfl-reduce at the end.
// ---------------------------------------------------------------------------
__global__ __launch_bounds__(256) void attn_mfma(
    const short* __restrict__ wh,   // (KLEN*BSZ, 3072) bf16
    const short* __restrict__ vt,   // (BSZ*NH, DH, KLEN) bf16
    const short* __restrict__ rk,   // (KLEN, NH*DH) bf16
    const float* __restrict__ rwb,
    const float* __restrict__ rrb,
    short* __restrict__ po,         // (2, 512, 64, 64) bf16
    float* __restrict__ ml)         // (2, 512, 64, 2) f32
{
    __shared__ __align__(16) short Ks[64 * 64];
    __shared__ __align__(16) short Vs[64 * 64];
    __shared__ __align__(16) short Rs[128 * 64];
    __shared__ __align__(16) short Ps[4][16 * 64];

    const int ib  = blockIdx.x;
    const int i0  = ib * 64;
    const int bn  = blockIdx.y;
    const int b   = bn >> 4, n = bn & 15;
    const int z   = blockIdx.z;
    const int tid = threadIdx.x;
    const int w   = tid >> 6;
    const int l   = tid & 63;
    const int lg  = l >> 4;
    const int lc  = l & 15;
    const int i_base = i0 + 16 * w;

    bf16x8 aqw[2], aqr[2];
    {
        const int i = i_base + lc;
        const short* qp = wh + ((size_t)(MTOT + i) * BSZ + b) * 3072 + n * 64;
        #pragma unroll
        for (int kc = 0; kc < 2; kc++) {
            const bf16x8 q8 = *(const bf16x8*)(qp + kc * 32 + lg * 8);
            const int d0 = kc * 32 + lg * 8;
            #pragma unroll
            for (int e = 0; e < 8; e++) {
                const float qv = bf2f(q8[e]);
                aqw[kc][e] = f2bf(qv + rwb[n * 64 + d0 + e]);
                aqr[kc][e] = f2bf(qv + rrb[n * 64 + d0 + e]);
            }
        }
    }

    f32x4 o_acc[4];
    #pragma unroll
    for (int nt = 0; nt < 4; nt++) o_acc[nt] = (f32x4){0.f, 0.f, 0.f, 0.f};
    float mrun[4]  = {0.f, 0.f, 0.f, 0.f};   // defer-max: start at 0
    float lpart[4] = {0.f, 0.f, 0.f, 0.f};   // per-lane partial sums

    const int jend   = i0 + 1600;
    const int jhalf  = (((jend >> 1) + 63) >> 6) << 6;
    const int jstart = z ? jhalf : 0;
    const int jstop  = z ? jend  : jhalf;

    for (int j0 = jstart; j0 < jstop; j0 += 64) {
        __syncthreads();
        #pragma unroll
        for (int u = 0; u < 2; u++) {
            const int ci  = tid * 2 + u;
            const int row = ci >> 3, c = ci & 7;
            const int sw  = (c ^ (row & 7)) * 8;
            const bf16x8 kv = *(const bf16x8*)(
                wh + ((size_t)(j0 + row) * BSZ + b) * 3072 + 1024 + n * 64 + c * 8);
            *(bf16x8*)(Ks + row * 64 + sw) = kv;
            const bf16x8 vv = *(const bf16x8*)(
                vt + ((size_t)(bn * 64) + row) * KLEN + j0 + c * 8);
            *(bf16x8*)(Vs + row * 64 + sw) = vv;
        }
        {
            const int mbase = j0 - i0 + 960;
            #pragma unroll
            for (int u = 0; u < 4; u++) {
                const int ci  = tid + 256 * u;
                const int row = ci >> 3, c = ci & 7;
                const int m   = mbase + row;
                bf16x8 rv = (bf16x8){0, 0, 0, 0, 0, 0, 0, 0};
                if (m < KLEN)
                    rv = *(const bf16x8*)(rk + (size_t)m * 1024 + n * 64 + c * 8);
                *(bf16x8*)(Rs + row * 64 + ((c ^ (row & 7)) * 8)) = rv;
            }
        }
        __syncthreads();

        f32x4 sfr[4];
        #pragma unroll
        for (int jt = 0; jt < 4; jt++) {
            const int row = 16 * jt + lc;
            const int c0 = (lg ^ (row & 7)) * 8, c1 = ((4 + lg) ^ (row & 7)) * 8;
            const bf16x8 bk0 = *(const bf16x8*)(Ks + row * 64 + c0);
            const bf16x8 bk1 = *(const bf16x8*)(Ks + row * 64 + c1);
            f32x4 acc = (f32x4){0.f, 0.f, 0.f, 0.f};
            acc = __builtin_amdgcn_mfma_f32_16x16x32_bf16(aqw[0], bk0, acc, 0, 0, 0);
            acc = __builtin_amdgcn_mfma_f32_16x16x32_bf16(aqw[1], bk1, acc, 0, 0, 0);
            sfr[jt] = acc;
        }
        f32x4 dr[5];
        #pragma unroll
        for (int mt = 0; mt < 5; mt++) {
            const int rrow = 16 * mt + lc + 48 - 16 * w;
            const int c0 = (lg ^ (rrow & 7)) * 8, c1 = ((4 + lg) ^ (rrow & 7)) * 8;
            const bf16x8 br0 = *(const bf16x8*)(Rs + rrow * 64 + c0);
            const bf16x8 br1 = *(const bf16x8*)(Rs + rrow * 64 + c1);
            f32x4 acc = (f32x4){0.f, 0.f, 0.f, 0.f};
            acc = __builtin_amdgcn_mfma_f32_16x16x32_bf16(aqr[0], br0, acc, 0, 0, 0);
            acc = __builtin_amdgcn_mfma_f32_16x16x32_bf16(aqr[1], br1, acc, 0, 0, 0);
            dr[mt] = acc;
        }

        // ---- rel-shift gather + defer-max softmax ----
        #pragma unroll
        for (int r = 0; r < 4; r++) {
            const int q   = 4 * lg + r;
            const int o   = lc + 15 - q;
            const int src = (l & 48) | (o & 15);
            float sv[4];
            float mx = -1e30f;
            #pragma unroll
            for (int jt = 0; jt < 4; jt++) {
                const float v0 = __shfl(dr[jt][r], src);
                const float v1 = __shfl(dr[jt + 1][r], src);
                const float bd = (o < 16) ? v0 : v1;
                float s = (sfr[jt][r] + bd) * 0.125f;
                if (z) {
                    const int j = j0 + 16 * jt + lc;
                    if (j > i_base + q + MTOT) s = -1e30f;
                }
                sv[jt] = s;
                mx = fmaxf(mx, s);
            }
            if (__any(mx - mrun[r] > 8.0f)) {   // rare slow path
                #pragma unroll
                for (int msk = 1; msk <= 8; msk <<= 1)
                    mx = fmaxf(mx, __shfl_xor(mx, msk));
                const float mnew = fmaxf(mrun[r], mx);
                const float corr = __expf(mrun[r] - mnew);
                mrun[r] = mnew;
                lpart[r] *= corr;
                #pragma unroll
                for (int nt = 0; nt < 4; nt++) o_acc[nt][r] *= corr;
            }
            float ps = 0.f;
            #pragma unroll
            for (int jt = 0; jt < 4; jt++) {
                const float p = __expf(sv[jt] - mrun[r]);
                ps += p;
                Ps[w][q * 64 + (((2 * jt + (lc >> 3)) ^ (q & 7)) * 8) + (lc & 7)] = f2bf(p);
            }
            lpart[r] += ps;
        }

        asm volatile("s_waitcnt lgkmcnt(0)" ::: "memory");
        __builtin_amdgcn_sched_barrier(0);

        // ---- O += P @ V ----
        const int pc0 = (lg ^ (lc & 7)) * 8, pc1 = ((4 + lg) ^ (lc & 7)) * 8;
        const bf16x8 pa0 = *(const bf16x8*)(Ps[w] + lc * 64 + pc0);
        const bf16x8 pa1 = *(const bf16x8*)(Ps[w] + lc * 64 + pc1);
        #pragma unroll
        for (int nt = 0; nt < 4; nt++) {
            const int row = 16 * nt + lc;
            const int c0 = (lg ^ (row & 7)) * 8, c1 = ((4 + lg) ^ (row & 7)) * 8;
            const bf16x8 bv0 = *(const bf16x8*)(Vs + row * 64 + c0);
            const bf16x8 bv1 = *(const bf16x8*)(Vs + row * 64 + c1);
            o_acc[nt] = __builtin_amdgcn_mfma_f32_16x16x32_bf16(pa0, bv0, o_acc[nt], 0, 0, 0);
            o_acc[nt] = __builtin_amdgcn_mfma_f32_16x16x32_bf16(pa1, bv1, o_acc[nt], 0, 0, 0);
        }
    }

    // ---- epilogue: reduce l once, write unnormalized partials ----
    const size_t blk = (size_t)z * 512 + ib * 32 + bn;
    #pragma unroll
    for (int r = 0; r < 4; r++) {
        float lr = lpart[r];
        #pragma unroll
        for (int msk = 1; msk <= 8; msk <<= 1)
            lr += __shfl_xor(lr, msk);
        const int q = 16 * w + 4 * lg + r;
        #pragma unroll
        for (int nt = 0; nt < 4; nt++)
            po[(blk * 64 + q) * 64 + 16 * nt + lc] = f2bf(o_acc[nt][r]);
        if (lc == 0) {
            ml[(blk * 64 + q) * 2 + 0] = mrun[r];
            ml[(blk * 64 + q) * 2 + 1] = lr;
        }
    }
}

// Merge the two split-K partials -> attn_vec (bf16). Grid (512), 256 thr.
__global__ __launch_bounds__(256) void attn_merge(
    const short* __restrict__ po, const float* __restrict__ ml,
    short* __restrict__ av)
{
    const int blk = blockIdx.x;
    const int ib = blk >> 5, bn = blk & 31;
    const int b = bn >> 4, n = bn & 15;
    const int tid = threadIdx.x;
    const int q = tid >> 2, dc = (tid & 3) * 16;
    const size_t r0 = (size_t)blk * 64 + q;
    const size_t r1 = (size_t)(512 + blk) * 64 + q;
    const float m0 = ml[r0 * 2], l0 = ml[r0 * 2 + 1];
    const float m1 = ml[r1 * 2], l1 = ml[r1 * 2 + 1];
    const float M = fmaxf(m0, m1);
    const float c0 = __expf(m0 - M), c1 = __expf(m1 - M);
    const float invL = 1.0f / (l0 * c0 + l1 * c1);
    const bf16x8 a0 = *(const bf16x8*)(po + r0 * 64 + dc);
    const bf16x8 a1 = *(const bf16x8*)(po + r0 * 64 + dc + 8);
    const bf16x8 b0 = *(const bf16x8*)(po + r1 * 64 + dc);
    const bf16x8 b1 = *(const bf16x8*)(po + r1 * 64 + dc + 8);
    __attribute__((aligned(16))) short ov[16];
    #pragma unroll
    for (int e = 0; e < 8; e++) {
        ov[e]     = f2bf((bf2f(a0[e]) * c0 + bf2f(b0[e]) * c1) * invL);
        ov[e + 8] = f2bf((bf2f(a1[e]) * c0 + bf2f(b1[e]) * c1) * invL);
    }
    const int i = ib * 64 + q;
    short* op = av + ((size_t)i * BSZ + b) * 1024 + n * 64 + dc;
    *(uint4*)op       = *(uint4*)ov;
    *(uint4*)(op + 8) = *((uint4*)ov + 1);
}

// ---------------------------------------------------------------------------
// Fused LayerNorm: out = LN(res + p0 + p1 (+ b2)) * scale + bias.
// WB: also write bf16 copy. Grid (2048), 256 thr.
// ---------------------------------------------------------------------------
template <bool WB, bool HASB>
__global__ __launch_bounds__(256) void ln_fuse(
    const float* __restrict__ p0, const float* __restrict__ p1,
    const float* __restrict__ badd, const float* __restrict__ res,
    const float* __restrict__ scale, const float* __restrict__ bias,
    float* __restrict__ out, short* __restrict__ outb)
{
    const int row = blockIdx.x;
    const int tid = threadIdx.x;
    const size_t base = (size_t)row * 1024 + tid * 4;
    const float4 a = *(const float4*)(p0 + base);
    const float4 b = *(const float4*)(p1 + base);
    const float4 rv = *(const float4*)(res + base);
    float v[4] = {a.x + b.x + rv.x, a.y + b.y + rv.y,
                  a.z + b.z + rv.z, a.w + b.w + rv.w};
    if (HASB) {
        const float4 bb = *(const float4*)(badd + tid * 4);
        v[0] += bb.x; v[1] += bb.y; v[2] += bb.z; v[3] += bb.w;
    }
    float s  = v[0] + v[1] + v[2] + v[3];
    float ss = v[0]*v[0] + v[1]*v[1] + v[2]*v[2] + v[3]*v[3];
    #pragma unroll
    for (int off = 32; off >= 1; off >>= 1) {
        s  += __shfl_down(s, off);
        ss += __shfl_down(ss, off);
    }
    __shared__ float red[8];
    const int lane = tid & 63, wid = tid >> 6;
    if (lane == 0) { red[wid] = s; red[4 + wid] = ss; }
    __syncthreads();
    if (tid == 0) {
        red[0] = red[0] + red[1] + red[2] + red[3];
        red[4] = red[4] + red[5] + red[6] + red[7];
    }
    __syncthreads();
    const float mean = red[0] * (1.0f / 1024.0f);
    const float var  = red[4] * (1.0f / 1024.0f) - mean * mean;
    const float rstd = rsqrtf(var + 1e-5f);
    const float4 sc = *(const float4*)(scale + tid * 4);
    const float4 bi = *(const float4*)(bias + tid * 4);
    float4 o;
    o.x = (v[0] - mean) * rstd * sc.x + bi.x;
    o.y = (v[1] - mean) * rstd * sc.y + bi.y;
    o.z = (v[2] - mean) * rstd * sc.z + bi.z;
    o.w = (v[3] - mean) * rstd * sc.w + bi.w;
    *(float4*)(out + base) = o;
    if (WB) {
        uint2 pk;
        pk.x = pack2(o.x, o.y);
        pk.y = pack2(o.z, o.w);
        *(uint2*)(outb + base) = pk;
    }
}

// ---------------------------------------------------------------------------
extern "C" void kernel_launch(void* const* d_in, const int* in_sizes, int n_in,
                              void* d_out, int out_size, void* d_ws, size_t ws_size,
                              hipStream_t stream) {
    const float* input_ids = (const float*)d_in[0];
    const float* pos_emb   = (const float*)d_in[1];
    const float* mem       = (const float*)d_in[2];
    const float* c_mem     = (const float*)d_in[3];
    const float* qkv_w     = (const float*)d_in[5];
    const float* r_w       = (const float*)d_in[6];
    const float* o_w       = (const float*)d_in[7];
    const float* r_w_bias  = (const float*)d_in[8];
    const float* r_r_bias  = (const float*)d_in[9];
    const float* ln_a_s    = (const float*)d_in[10];
    const float* ln_a_b    = (const float*)d_in[11];
    const float* ff_w1     = (const float*)d_in[12];
    const float* ff_b1     = (const float*)d_in[13];
    const float* ff_w2     = (const float*)d_in[14];
    const float* ff_b2     = (const float*)d_in[15];
    const float* ln_f_s    = (const float*)d_in[16];
    const float* ln_f_b    = (const float*)d_in[17];

    char* base = (char*)d_ws;
    // persistent weights
    short* o_wt   = (short*)(base + 0);          // 1024x1024
    short* ff1t   = (short*)(base + 2097152);    // 4096x1024
    short* ff2t   = (short*)(base + 10485760);   // 1024x4096
    // phase 1
    short* whb    = (short*)(base + 18874368);   // 5120x3072
    short* rkb    = (short*)(base + 50331648);   // 2560x1024
    short* qkv_wt = (short*)(base + 55574528);   // 3072x1024  [dead after G1]
    short* catb   = (short*)(base + 61865984);   // 5120x1024  [dead after G1]
    short* posb   = (short*)(base + 72351744);   // 2560x1024  [dead after G2]
    short* r_wt   = (short*)(base + 77594624);   // 1024x1024  [dead after G2]
    // phase 2 overlays (over dead prep temps)
    short* vtb    = (short*)(base + 55574528);   // 2x16x64x2560
    short* po     = (short*)(base + 66060288);   // 2x512x64x64
    float* mlb    = (float*)(base + 74448896);   // 2x512x64x2
    short* avb    = (short*)(base + 74973184);   // 2048x1024
    // phase 3 overlays (over dead whb/rkb/vtb/po)
    float* hp0    = (float*)(base + 18874368);   // 2048x1024 f32 partial
    float* hp1    = (float*)(base + 27262976);   // 2048x1024 f32 partial
    float* ares   = (float*)(base + 35651584);   // 2048x1024 f32
    short* aresb  = (short*)(base + 44040192);   // 2048x1024
    short* h1b    = (short*)(base + 48234496);   // 2048x4096

    const dim3 thr(256);

    // 0) all conversions/transposes in one launch
    prep_all<<<dim3(7168), thr, 0, stream>>>(
        mem, c_mem, input_ids, catb, pos_emb, posb,
        qkv_w, qkv_wt, r_w, r_wt, o_w, o_wt, ff_w1, ff1t, ff_w2, ff2t);
    // 1+2) w_heads + r_k in one launch
    gemm_g12<<<dim3(1120), thr, 0, stream>>>(catb, qkv_wt, whb, posb, r_wt, rkb);
    // 3) V^T materialization
    vt_conv<<<dim3(40, 32), thr, 0, stream>>>(whb, vtb);
    // 4) split-K flash attention + merge
    attn_mfma<<<dim3(16, 32, 2), thr, 0, stream>>>(
        whb, vtb, rkb, r_w_bias, r_r_bias, po, mlb);
    attn_merge<<<dim3(512), thr, 0, stream>>>(po, mlb, avb);
    // 5) attn_out = avb @ o_w, split-K 2x (K=1024 -> 512)
    gemm_split<<<dim3(8, 16, 2), thr, 0, stream>>>(
        avb, o_wt, hp0, hp1, 1024, 1024, 512);
    // 6) attn_res = LN(input + hp0 + hp1)
    ln_fuse<true, false><<<dim3(2048), thr, 0, stream>>>(
        hp0, hp1, nullptr, input_ids, ln_a_s, ln_a_b, ares, aresb);
    // 7) h1 = relu(ares @ ff_w1 + b1)
    gemm_relu<<<dim3(32, 16), thr, 0, stream>>>(aresb, ff1t, ff_b1, h1b, 4096, 1024);
    // 8) h2-partials = h1 @ ff_w2, split-K 2x (K=4096 -> 2048)
    gemm_split<<<dim3(8, 16, 2), thr, 0, stream>>>(
        h1b, ff2t, hp0, hp1, 1024, 4096, 2048);
    // 9) out = LN(ares + hp0 + hp1 + b2)
    ln_fuse<false, true><<<dim3(2048), thr, 0, stream>>>(
        hp0, hp1, ff_b2, ares, ln_f_s, ln_f_b, (float*)d_out, nullptr);
}

// Round 7
// 295.029 us; speedup vs baseline: 1.4463x; 1.0940x over previous
//
#include <hip/hip_runtime.h>
#include <hip/hip_bf16.h>

#define QLEN 1024
#define KLEN 2560
#define MTOT 1536   // KLEN - QLEN
#define BSZ 2
#define NH 16
#define DH 64
#define DMODEL 1024
#define DINNER 4096

typedef short bf16x8 __attribute__((ext_vector_type(8)));
typedef float f32x4  __attribute__((ext_vector_type(4)));

__device__ __forceinline__ short f2bf(float f) {
    union { float f; unsigned u; } v; v.f = f;
    unsigned r = v.u + 0x7FFFu + ((v.u >> 16) & 1u);
    return (short)(r >> 16);
}
__device__ __forceinline__ float bf2f(short s) {
    union { unsigned u; float f; } v; v.u = ((unsigned)(unsigned short)s) << 16;
    return v.f;
}
__device__ __forceinline__ unsigned pack2(float a, float b) {
    return (unsigned)(unsigned short)f2bf(a) | ((unsigned)(unsigned short)f2bf(b) << 16);
}

#define GLOAD16(g, l)                                                        \
    __builtin_amdgcn_global_load_lds(                                        \
        (const __attribute__((address_space(1))) unsigned int*)(g),          \
        (__attribute__((address_space(3))) unsigned int*)(l), 16, 0, 0)

// ---------------------------------------------------------------------------
// prep_all: all input conversions/transposes in ONE launch (range dispatch).
// ---------------------------------------------------------------------------
__device__ __forceinline__ void tr_body(
    const float* __restrict__ in, short* __restrict__ out,
    int K, int N, int bx, int by, int tid, float (*ts)[65])
{
    const int k0 = by * 64, n0 = bx * 64;
    const int r = tid >> 2, cb = (tid & 3) * 16;
    #pragma unroll
    for (int u = 0; u < 16; u += 4) {
        const float4 v = *(const float4*)(in + (size_t)(k0 + r) * N + n0 + cb + u);
        ts[r][cb + u] = v.x; ts[r][cb + u + 1] = v.y;
        ts[r][cb + u + 2] = v.z; ts[r][cb + u + 3] = v.w;
    }
    __syncthreads();
    #pragma unroll
    for (int p = 0; p < 4; p++) {
        const int wr_ = (tid >> 4) + p * 16;
        const int c   = (tid & 15) * 4;
        uint2 pk;
        pk.x = pack2(ts[c][wr_], ts[c + 1][wr_]);
        pk.y = pack2(ts[c + 2][wr_], ts[c + 3][wr_]);
        *(uint2*)(out + (size_t)(n0 + wr_) * K + k0 + c) = pk;
    }
}

__global__ __launch_bounds__(256) void prep_all(
    const float* __restrict__ mem, const float* __restrict__ cmem,
    const float* __restrict__ inp, short* __restrict__ catb,
    const float* __restrict__ pos, short* __restrict__ posb,
    const float* __restrict__ qkv_w, short* __restrict__ qkv_wt,
    const float* __restrict__ r_w, short* __restrict__ r_wt,
    const float* __restrict__ o_w, short* __restrict__ o_wt,
    const float* __restrict__ ff_w1, short* __restrict__ ff1t,
    const float* __restrict__ ff_w2, short* __restrict__ ff2t)
{
    __shared__ float ts[64][65];
    const int bid = blockIdx.x;
    const int tid = threadIdx.x;
    if (bid < 2560) {
        const int i = bid * 256 + tid;
        const int row = i >> 7, c = (i & 127) * 8;
        const float* src;
        if (row < 2048)      src = mem  + (size_t)row * 1024;
        else if (row < 3072) src = cmem + (size_t)(row - 2048) * 1024;
        else                 src = inp  + (size_t)(row - 3072) * 1024;
        const float4 a = *(const float4*)(src + c);
        const float4 b = *(const float4*)(src + c + 4);
        uint4 o;
        o.x = pack2(a.x, a.y); o.y = pack2(a.z, a.w);
        o.z = pack2(b.x, b.y); o.w = pack2(b.z, b.w);
        *(uint4*)(catb + (size_t)i * 8) = o;
    } else if (bid < 3840) {
        const int i = (bid - 2560) * 256 + tid;
        const float4 a = *(const float4*)(pos + (size_t)i * 8);
        const float4 b = *(const float4*)(pos + (size_t)i * 8 + 4);
        uint4 o;
        o.x = pack2(a.x, a.y); o.y = pack2(a.z, a.w);
        o.z = pack2(b.x, b.y); o.w = pack2(b.z, b.w);
        *(uint4*)(posb + (size_t)i * 8) = o;
    } else if (bid < 4608) {
        const int r = bid - 3840; tr_body(qkv_w, qkv_wt, 1024, 3072, r % 48, r / 48, tid, ts);
    } else if (bid < 4864) {
        const int r = bid - 4608; tr_body(r_w, r_wt, 1024, 1024, r % 16, r / 16, tid, ts);
    } else if (bid < 5120) {
        const int r = bid - 4864; tr_body(o_w, o_wt, 1024, 1024, r % 16, r / 16, tid, ts);
    } else if (bid < 6144) {
        const int r = bid - 5120; tr_body(ff_w1, ff1t, 1024, 4096, r % 64, r / 64, tid, ts);
    } else {
        const int r = bid - 6144; tr_body(ff_w2, ff2t, 4096, 1024, r % 16, r / 16, tid, ts);
    }
}

// whb V-part (key-major) -> vtb (BSZ*NH, DH, KLEN) key-minor. Grid (40, 32).
__global__ __launch_bounds__(256) void vt_conv(
    const short* __restrict__ wh, short* __restrict__ vt)
{
    __shared__ short Ts[64][72];
    const int j0 = blockIdx.x * 64;
    const int bn = blockIdx.y;
    const int b = bn >> 4, n = bn & 15;
    const int tid = threadIdx.x;
    {
        const int key = tid >> 2, c = (tid & 3) * 16;
        const short* p = wh + ((size_t)(j0 + key) * BSZ + b) * 3072 + 2048 + n * 64 + c;
        *(bf16x8*)&Ts[key][c]     = *(const bf16x8*)p;
        *(bf16x8*)&Ts[key][c + 8] = *(const bf16x8*)(p + 8);
    }
    __syncthreads();
    {
        const int d = tid >> 2, kc = (tid & 3) * 16;
        __attribute__((aligned(16))) short tmp[16];
        #pragma unroll
        for (int u = 0; u < 16; u++) tmp[u] = Ts[kc + u][d];
        short* q = vt + ((size_t)(bn * 64) + d) * KLEN + j0 + kc;
        *(uint4*)q       = *(uint4*)tmp;
        *(uint4*)(q + 8) = *((uint4*)tmp + 1);
    }
}

// ---------------------------------------------------------------------------
// Shared m97 GEMM core: 128x128 tile, BK=32, 4 waves, global_load_lds staging.
// ---------------------------------------------------------------------------
__device__ __forceinline__ void gemm_core(
    const short* __restrict__ A, const short* __restrict__ Bt,
    short* As, short* Bs, int Kfull, int klen, int bm, int bn,
    int tid, f32x4 acc[4][4])
{
    const int w  = tid >> 6;
    const int l  = tid & 63;
    const int lg = l >> 4, lc = l & 15;
    const int wr = w >> 1, wc = w & 1;
    const int srow = 2 * w * 16 + (l >> 2);
    const int scol = (l & 3) * 8;
    const size_t aoff0 = (size_t)(bm + srow) * Kfull + scol;
    const size_t boff0 = (size_t)(bn + srow) * Kfull + scol;
    const size_t rstep = (size_t)16 * Kfull;
    short* lA0 = As + 2 * w * 512;
    short* lA1 = As + (2 * w + 1) * 512;
    short* lB0 = Bs + 2 * w * 512;
    short* lB1 = Bs + (2 * w + 1) * 512;

    for (int k0 = 0; k0 < klen; k0 += 32) {
        GLOAD16(A + aoff0 + k0, lA0);
        GLOAD16(A + aoff0 + rstep + k0, lA1);
        GLOAD16(Bt + boff0 + k0, lB0);
        GLOAD16(Bt + boff0 + rstep + k0, lB1);
        __syncthreads();
        bf16x8 af[4], bfr[4];
        #pragma unroll
        for (int m = 0; m < 4; m++)
            af[m] = *(const bf16x8*)(As + (wr * 64 + m * 16 + lc) * 32 + lg * 8);
        #pragma unroll
        for (int n = 0; n < 4; n++)
            bfr[n] = *(const bf16x8*)(Bs + (wc * 64 + n * 16 + lc) * 32 + lg * 8);
        #pragma unroll
        for (int m = 0; m < 4; m++)
            #pragma unroll
            for (int n = 0; n < 4; n++)
                acc[m][n] = __builtin_amdgcn_mfma_f32_16x16x32_bf16(
                    af[m], bfr[n], acc[m][n], 0, 0, 0);
        __syncthreads();
    }
}

// G1 (w_heads) + G2 (r_k) in one launch: blocks [0,960) G1, [960,1120) G2.
__global__ __launch_bounds__(256) void gemm_g12(
    const short* __restrict__ catb, const short* __restrict__ qkv_wt,
    short* __restrict__ whb,
    const short* __restrict__ posb, const short* __restrict__ r_wt,
    short* __restrict__ rkb)
{
    __shared__ short As[4096], Bs[4096];
    const int tid = threadIdx.x;
    int id = blockIdx.x;
    const short *A, *Bt; short* Cb; int N, bm, bn;
    if (id < 960) { A = catb; Bt = qkv_wt; Cb = whb; N = 3072;
                    bm = (id / 24) * 128; bn = (id % 24) * 128; }
    else { id -= 960; A = posb; Bt = r_wt; Cb = rkb; N = 1024;
           bm = (id / 8) * 128; bn = (id % 8) * 128; }

    f32x4 acc[4][4];
    #pragma unroll
    for (int m = 0; m < 4; m++)
        #pragma unroll
        for (int n = 0; n < 4; n++) acc[m][n] = (f32x4){0.f, 0.f, 0.f, 0.f};
    gemm_core(A, Bt, As, Bs, 1024, 1024, bm, bn, tid, acc);

    const int w = tid >> 6, l = tid & 63, lg = l >> 4, lc = l & 15;
    const int wr = w >> 1, wc = w & 1;
    #pragma unroll
    for (int m = 0; m < 4; m++)
        #pragma unroll
        for (int n = 0; n < 4; n++) {
            const int col = bn + wc * 64 + n * 16 + lc;
            #pragma unroll
            for (int r = 0; r < 4; r++) {
                const int row = bm + wr * 64 + m * 16 + lg * 4 + r;
                Cb[(size_t)row * N + col] = f2bf(acc[m][n][r]);
            }
        }
}

// G7: h1 = relu(ares @ ff_w1 + b1), bf16 out. Grid (N/128, M/128).
__global__ __launch_bounds__(256) void gemm_relu(
    const short* __restrict__ A, const short* __restrict__ Bt,
    const float* __restrict__ bias, short* __restrict__ Cb,
    int N, int K)
{
    __shared__ short As[4096], Bs[4096];
    const int tid = threadIdx.x;
    const int bm = blockIdx.y * 128, bn = blockIdx.x * 128;
    f32x4 acc[4][4];
    #pragma unroll
    for (int m = 0; m < 4; m++)
        #pragma unroll
        for (int n = 0; n < 4; n++) acc[m][n] = (f32x4){0.f, 0.f, 0.f, 0.f};
    gemm_core(A, Bt, As, Bs, K, K, bm, bn, tid, acc);

    const int w = tid >> 6, l = tid & 63, lg = l >> 4, lc = l & 15;
    const int wr = w >> 1, wc = w & 1;
    #pragma unroll
    for (int m = 0; m < 4; m++)
        #pragma unroll
        for (int n = 0; n < 4; n++) {
            const int col = bn + wc * 64 + n * 16 + lc;
            const float bv = bias[col];
            #pragma unroll
            for (int r = 0; r < 4; r++) {
                const int row = bm + wr * 64 + m * 16 + lg * 4 + r;
                Cb[(size_t)row * N + col] = f2bf(fmaxf(acc[m][n][r] + bv, 0.0f));
            }
        }
}

// Split-K GEMM partial: z in {0,1} computes K-range [z*Ksub, (z+1)*Ksub),
// writing f32 partial to C0/C1. Grid (N/128, M/128, 2).
__global__ __launch_bounds__(256) void gemm_split(
    const short* __restrict__ A, const short* __restrict__ Bt,
    float* __restrict__ C0, float* __restrict__ C1,
    int N, int Kfull, int Ksub)
{
    __shared__ short As[4096], Bs[4096];
    const int tid = threadIdx.x;
    const int z = blockIdx.z;
    const int bm = blockIdx.y * 128, bn = blockIdx.x * 128;
    float* C = z ? C1 : C0;
    f32x4 acc[4][4];
    #pragma unroll
    for (int m = 0; m < 4; m++)
        #pragma unroll
        for (int n = 0; n < 4; n++) acc[m][n] = (f32x4){0.f, 0.f, 0.f, 0.f};
    gemm_core(A + z * Ksub, Bt + z * Ksub, As, Bs, Kfull, Ksub, bm, bn, tid, acc);

    const int w = tid >> 6, l = tid & 63, lg = l >> 4, lc = l & 15;
    const int wr = w >> 1, wc = w & 1;
    #pragma unroll
    for (int m = 0; m < 4; m++)
        #pragma unroll
        for (int n = 0; n < 4; n++) {
            const int col = bn + wc * 64 + n * 16 + lc;
            #pragma unroll
            for (int r = 0; r < 4; r++) {
                const int row = bm + wr * 64 + m * 16 + lg * 4 + r;
                C[(size_t)row * N + col] = acc[m][n][r];
            }
        }
}

// ---------------------------------------------------------------------------
// MFMA flash attention: 2-way split-K, XOR-swizzled LDS, defer-max softmax,
// XCD-aware 1D launch (blocks sharing bn co-locate on one XCD for L2 reuse),
// K/V register prefetch across j-tiles (async-stage), setprio around MFMA.
// Grid: 1024 blocks 1D. Decode: ib=(bid>>3)&15, z=(bid>>7)&1,
//       bn=((bid&7)<<2)|(bid>>8)   [bijection; bn's 32 blocks -> one XCD]
// ---------------------------------------------------------------------------
__global__ __launch_bounds__(256) void attn_mfma(
    const short* __restrict__ wh,   // (KLEN*BSZ, 3072) bf16
    const short* __restrict__ vt,   // (BSZ*NH, DH, KLEN) bf16
    const short* __restrict__ rk,   // (KLEN, NH*DH) bf16
    const float* __restrict__ rwb,
    const float* __restrict__ rrb,
    short* __restrict__ po,         // (2, 512, 64, 64) bf16
    float* __restrict__ ml)         // (2, 512, 64, 2) f32
{
    __shared__ __align__(16) short Ks[64 * 64];
    __shared__ __align__(16) short Vs[64 * 64];
    __shared__ __align__(16) short Rs[128 * 64];
    __shared__ __align__(16) short Ps[4][16 * 64];

    const int bid = blockIdx.x;
    const int ib  = (bid >> 3) & 15;
    const int z   = (bid >> 7) & 1;
    const int bn  = ((bid & 7) << 2) | (bid >> 8);
    const int i0  = ib * 64;
    const int b   = bn >> 4, n = bn & 15;
    const int tid = threadIdx.x;
    const int w   = tid >> 6;
    const int l   = tid & 63;
    const int lg  = l >> 4;
    const int lc  = l & 15;
    const int i_base = i0 + 16 * w;

    bf16x8 aqw[2], aqr[2];
    {
        const int i = i_base + lc;
        const short* qp = wh + ((size_t)(MTOT + i) * BSZ + b) * 3072 + n * 64;
        #pragma unroll
        for (int kc = 0; kc < 2; kc++) {
            const bf16x8 q8 = *(const bf16x8*)(qp + kc * 32 + lg * 8);
            const int d0 = kc * 32 + lg * 8;
            #pragma unroll
            for (int e = 0; e < 8; e++) {
                const float qv = bf2f(q8[e]);
                aqw[kc][e] = f2bf(qv + rwb[n * 64 + d0 + e]);
                aqr[kc][e] = f2bf(qv + rrb[n * 64 + d0 + e]);
            }
        }
    }

    f32x4 o_acc[4];
    #pragma unroll
    for (int nt = 0; nt < 4; nt++) o_acc[nt] = (f32x4){0.f, 0.f, 0.f, 0.f};
    float mrun[4]  = {0.f, 0.f, 0.f, 0.f};
    float lpart[4] = {0.f, 0.f, 0.f, 0.f};

    const int jend   = i0 + 1600;
    const int jhalf  = (((jend >> 1) + 63) >> 6) << 6;
    const int jstart = z ? jhalf : 0;
    const int jstop  = z ? jend  : jhalf;

    // K/V prefetch lane mapping (2 chunks/thread)
    const int kr0 = (tid * 2) >> 3,     kc0 = (tid * 2) & 7;
    const int kr1 = (tid * 2 + 1) >> 3, kc1 = (tid * 2 + 1) & 7;
    const size_t whK = (size_t)b * 3072 + 1024 + n * 64;   // + (j)*BSZ*3072
    const size_t vtK = (size_t)(bn * 64) * KLEN;           // + row*KLEN + j

    bf16x8 pk0, pk1, pv0, pv1;
    pk0 = *(const bf16x8*)(wh + (size_t)(jstart + kr0) * BSZ * 3072 + whK + kc0 * 8);
    pk1 = *(const bf16x8*)(wh + (size_t)(jstart + kr1) * BSZ * 3072 + whK + kc1 * 8);
    pv0 = *(const bf16x8*)(vt + vtK + (size_t)kr0 * KLEN + jstart + kc0 * 8);
    pv1 = *(const bf16x8*)(vt + vtK + (size_t)kr1 * KLEN + jstart + kc1 * 8);

    for (int j0 = jstart; j0 < jstop; j0 += 64) {
        __syncthreads();   // previous tile's compute done reading LDS
        // ---- issue R loads (L2-hot with XCD swizzle) ----
        bf16x8 rreg[4];
        const int mbase = j0 - i0 + 960;
        #pragma unroll
        for (int u = 0; u < 4; u++) {
            const int ci  = tid + 256 * u;
            const int row = ci >> 3, c = ci & 7;
            const int m   = mbase + row;
            rreg[u] = (m < KLEN)
                ? *(const bf16x8*)(rk + (size_t)m * 1024 + n * 64 + c * 8)
                : (bf16x8){0, 0, 0, 0, 0, 0, 0, 0};
        }
        // ---- write prefetched K/V to LDS (swizzled) ----
        *(bf16x8*)(Ks + kr0 * 64 + ((kc0 ^ (kr0 & 7)) * 8)) = pk0;
        *(bf16x8*)(Ks + kr1 * 64 + ((kc1 ^ (kr1 & 7)) * 8)) = pk1;
        *(bf16x8*)(Vs + kr0 * 64 + ((kc0 ^ (kr0 & 7)) * 8)) = pv0;
        *(bf16x8*)(Vs + kr1 * 64 + ((kc1 ^ (kr1 & 7)) * 8)) = pv1;
        // ---- write R ----
        #pragma unroll
        for (int u = 0; u < 4; u++) {
            const int ci  = tid + 256 * u;
            const int row = ci >> 3, c = ci & 7;
            *(bf16x8*)(Rs + row * 64 + ((c ^ (row & 7)) * 8)) = rreg[u];
        }
        // ---- prefetch next tile's K/V (latency hides under compute) ----
        const int jn = j0 + 64;
        if (jn < jstop) {
            pk0 = *(const bf16x8*)(wh + (size_t)(jn + kr0) * BSZ * 3072 + whK + kc0 * 8);
            pk1 = *(const bf16x8*)(wh + (size_t)(jn + kr1) * BSZ * 3072 + whK + kc1 * 8);
            pv0 = *(const bf16x8*)(vt + vtK + (size_t)kr0 * KLEN + jn + kc0 * 8);
            pv1 = *(const bf16x8*)(vt + vtK + (size_t)kr1 * KLEN + jn + kc1 * 8);
        }
        __syncthreads();   // staging visible

        // ---- AC = (Q+rwb) @ K^T ----
        __builtin_amdgcn_s_setprio(1);
        f32x4 sfr[4];
        #pragma unroll
        for (int jt = 0; jt < 4; jt++) {
            const int row = 16 * jt + lc;
            const int c0 = (lg ^ (row & 7)) * 8, c1 = ((4 + lg) ^ (row & 7)) * 8;
            const bf16x8 bk0 = *(const bf16x8*)(Ks + row * 64 + c0);
            const bf16x8 bk1 = *(const bf16x8*)(Ks + row * 64 + c1);
            f32x4 acc = (f32x4){0.f, 0.f, 0.f, 0.f};
            acc = __builtin_amdgcn_mfma_f32_16x16x32_bf16(aqw[0], bk0, acc, 0, 0, 0);
            acc = __builtin_amdgcn_mfma_f32_16x16x32_bf16(aqw[1], bk1, acc, 0, 0, 0);
            sfr[jt] = acc;
        }
        // ---- Dr = (Q+rrb) @ R^T (80 shift positions) ----
        f32x4 dr[5];
        #pragma unroll
        for (int mt = 0; mt < 5; mt++) {
            const int rrow = 16 * mt + lc + 48 - 16 * w;
            const int c0 = (lg ^ (rrow & 7)) * 8, c1 = ((4 + lg) ^ (rrow & 7)) * 8;
            const bf16x8 br0 = *(const bf16x8*)(Rs + rrow * 64 + c0);
            const bf16x8 br1 = *(const bf16x8*)(Rs + rrow * 64 + c1);
            f32x4 acc = (f32x4){0.f, 0.f, 0.f, 0.f};
            acc = __builtin_amdgcn_mfma_f32_16x16x32_bf16(aqr[0], br0, acc, 0, 0, 0);
            acc = __builtin_amdgcn_mfma_f32_16x16x32_bf16(aqr[1], br1, acc, 0, 0, 0);
            dr[mt] = acc;
        }
        __builtin_amdgcn_s_setprio(0);

        // ---- rel-shift gather + defer-max softmax ----
        #pragma unroll
        for (int r = 0; r < 4; r++) {
            const int q   = 4 * lg + r;
            const int o   = lc + 15 - q;
            const int src = (l & 48) | (o & 15);
            float sv[4];
            float mx = -1e30f;
            #pragma unroll
            for (int jt = 0; jt < 4; jt++) {
                const float v0 = __shfl(dr[jt][r], src);
                const float v1 = __shfl(dr[jt + 1][r], src);
                const float bd = (o < 16) ? v0 : v1;
                float s = (sfr[jt][r] + bd) * 0.125f;
                if (z) {
                    const int j = j0 + 16 * jt + lc;
                    if (j > i_base + q + MTOT) s = -1e30f;
                }
                sv[jt] = s;
                mx = fmaxf(mx, s);
            }
            if (__any(mx - mrun[r] > 8.0f)) {   // rare slow path
                #pragma unroll
                for (int msk = 1; msk <= 8; msk <<= 1)
                    mx = fmaxf(mx, __shfl_xor(mx, msk));
                const float mnew = fmaxf(mrun[r], mx);
                const float corr = __expf(mrun[r] - mnew);
                mrun[r] = mnew;
                lpart[r] *= corr;
                #pragma unroll
                for (int nt = 0; nt < 4; nt++) o_acc[nt][r] *= corr;
            }
            float ps = 0.f;
            #pragma unroll
            for (int jt = 0; jt < 4; jt++) {
                const float p = __expf(sv[jt] - mrun[r]);
                ps += p;
                Ps[w][q * 64 + (((2 * jt + (lc >> 3)) ^ (q & 7)) * 8) + (lc & 7)] = f2bf(p);
            }
            lpart[r] += ps;
        }

        asm volatile("s_waitcnt lgkmcnt(0)" ::: "memory");
        __builtin_amdgcn_sched_barrier(0);

        // ---- O += P @ V ----
        __builtin_amdgcn_s_setprio(1);
        const int pc0 = (lg ^ (lc & 7)) * 8, pc1 = ((4 + lg) ^ (lc & 7)) * 8;
        const bf16x8 pa0 = *(const bf16x8*)(Ps[w] + lc * 64 + pc0);
        const bf16x8 pa1 = *(const bf16x8*)(Ps[w] + lc * 64 + pc1);
        #pragma unroll
        for (int nt = 0; nt < 4; nt++) {
            const int row = 16 * nt + lc;
            const int c0 = (lg ^ (row & 7)) * 8, c1 = ((4 + lg) ^ (row & 7)) * 8;
            const bf16x8 bv0 = *(const bf16x8*)(Vs + row * 64 + c0);
            const bf16x8 bv1 = *(const bf16x8*)(Vs + row * 64 + c1);
            o_acc[nt] = __builtin_amdgcn_mfma_f32_16x16x32_bf16(pa0, bv0, o_acc[nt], 0, 0, 0);
            o_acc[nt] = __builtin_amdgcn_mfma_f32_16x16x32_bf16(pa1, bv1, o_acc[nt], 0, 0, 0);
        }
        __builtin_amdgcn_s_setprio(0);
    }

    // ---- epilogue: reduce l once, write unnormalized partials ----
    const size_t blk = (size_t)z * 512 + ib * 32 + bn;
    #pragma unroll
    for (int r = 0; r < 4; r++) {
        float lr = lpart[r];
        #pragma unroll
        for (int msk = 1; msk <= 8; msk <<= 1)
            lr += __shfl_xor(lr, msk);
        const int q = 16 * w + 4 * lg + r;
        #pragma unroll
        for (int nt = 0; nt < 4; nt++)
            po[(blk * 64 + q) * 64 + 16 * nt + lc] = f2bf(o_acc[nt][r]);
        if (lc == 0) {
            ml[(blk * 64 + q) * 2 + 0] = mrun[r];
            ml[(blk * 64 + q) * 2 + 1] = lr;
        }
    }
}

// Merge the two split-K partials -> attn_vec (bf16). Grid (512), 256 thr.
__global__ __launch_bounds__(256) void attn_merge(
    const short* __restrict__ po, const float* __restrict__ ml,
    short* __restrict__ av)
{
    const int blk = blockIdx.x;
    const int ib = blk >> 5, bn = blk & 31;
    const int b = bn >> 4, n = bn & 15;
    const int tid = threadIdx.x;
    const int q = tid >> 2, dc = (tid & 3) * 16;
    const size_t r0 = (size_t)blk * 64 + q;
    const size_t r1 = (size_t)(512 + blk) * 64 + q;
    const float m0 = ml[r0 * 2], l0 = ml[r0 * 2 + 1];
    const float m1 = ml[r1 * 2], l1 = ml[r1 * 2 + 1];
    const float M = fmaxf(m0, m1);
    const float c0 = __expf(m0 - M), c1 = __expf(m1 - M);
    const float invL = 1.0f / (l0 * c0 + l1 * c1);
    const bf16x8 a0 = *(const bf16x8*)(po + r0 * 64 + dc);
    const bf16x8 a1 = *(const bf16x8*)(po + r0 * 64 + dc + 8);
    const bf16x8 b0 = *(const bf16x8*)(po + r1 * 64 + dc);
    const bf16x8 b1 = *(const bf16x8*)(po + r1 * 64 + dc + 8);
    __attribute__((aligned(16))) short ov[16];
    #pragma unroll
    for (int e = 0; e < 8; e++) {
        ov[e]     = f2bf((bf2f(a0[e]) * c0 + bf2f(b0[e]) * c1) * invL);
        ov[e + 8] = f2bf((bf2f(a1[e]) * c0 + bf2f(b1[e]) * c1) * invL);
    }
    const int i = ib * 64 + q;
    short* op = av + ((size_t)i * BSZ + b) * 1024 + n * 64 + dc;
    *(uint4*)op       = *(uint4*)ov;
    *(uint4*)(op + 8) = *((uint4*)ov + 1);
}

// ---------------------------------------------------------------------------
// Fused LayerNorm: out = LN(res + p0 + p1 (+ b2)) * scale + bias.
// ---------------------------------------------------------------------------
template <bool WB, bool HASB>
__global__ __launch_bounds__(256) void ln_fuse(
    const float* __restrict__ p0, const float* __restrict__ p1,
    const float* __restrict__ badd, const float* __restrict__ res,
    const float* __restrict__ scale, const float* __restrict__ bias,
    float* __restrict__ out, short* __restrict__ outb)
{
    const int row = blockIdx.x;
    const int tid = threadIdx.x;
    const size_t base = (size_t)row * 1024 + tid * 4;
    const float4 a = *(const float4*)(p0 + base);
    const float4 b = *(const float4*)(p1 + base);
    const float4 rv = *(const float4*)(res + base);
    float v[4] = {a.x + b.x + rv.x, a.y + b.y + rv.y,
                  a.z + b.z + rv.z, a.w + b.w + rv.w};
    if (HASB) {
        const float4 bb = *(const float4*)(badd + tid * 4);
        v[0] += bb.x; v[1] += bb.y; v[2] += bb.z; v[3] += bb.w;
    }
    float s  = v[0] + v[1] + v[2] + v[3];
    float ss = v[0]*v[0] + v[1]*v[1] + v[2]*v[2] + v[3]*v[3];
    #pragma unroll
    for (int off = 32; off >= 1; off >>= 1) {
        s  += __shfl_down(s, off);
        ss += __shfl_down(ss, off);
    }
    __shared__ float red[8];
    const int lane = tid & 63, wid = tid >> 6;
    if (lane == 0) { red[wid] = s; red[4 + wid] = ss; }
    __syncthreads();
    if (tid == 0) {
        red[0] = red[0] + red[1] + red[2] + red[3];
        red[4] = red[4] + red[5] + red[6] + red[7];
    }
    __syncthreads();
    const float mean = red[0] * (1.0f / 1024.0f);
    const float var  = red[4] * (1.0f / 1024.0f) - mean * mean;
    const float rstd = rsqrtf(var + 1e-5f);
    const float4 sc = *(const float4*)(scale + tid * 4);
    const float4 bi = *(const float4*)(bias + tid * 4);
    float4 o;
    o.x = (v[0] - mean) * rstd * sc.x + bi.x;
    o.y = (v[1] - mean) * rstd * sc.y + bi.y;
    o.z = (v[2] - mean) * rstd * sc.z + bi.z;
    o.w = (v[3] - mean) * rstd * sc.w + bi.w;
    *(float4*)(out + base) = o;
    if (WB) {
        uint2 pk;
        pk.x = pack2(o.x, o.y);
        pk.y = pack2(o.z, o.w);
        *(uint2*)(outb + base) = pk;
    }
}

// ---------------------------------------------------------------------------
extern "C" void kernel_launch(void* const* d_in, const int* in_sizes, int n_in,
                              void* d_out, int out_size, void* d_ws, size_t ws_size,
                              hipStream_t stream) {
    const float* input_ids = (const float*)d_in[0];
    const float* pos_emb   = (const float*)d_in[1];
    const float* mem       = (const float*)d_in[2];
    const float* c_mem     = (const float*)d_in[3];
    const float* qkv_w     = (const float*)d_in[5];
    const float* r_w       = (const float*)d_in[6];
    const float* o_w       = (const float*)d_in[7];
    const float* r_w_bias  = (const float*)d_in[8];
    const float* r_r_bias  = (const float*)d_in[9];
    const float* ln_a_s    = (const float*)d_in[10];
    const float* ln_a_b    = (const float*)d_in[11];
    const float* ff_w1     = (const float*)d_in[12];
    const float* ff_b1     = (const float*)d_in[13];
    const float* ff_w2     = (const float*)d_in[14];
    const float* ff_b2     = (const float*)d_in[15];
    const float* ln_f_s    = (const float*)d_in[16];
    const float* ln_f_b    = (const float*)d_in[17];

    char* base = (char*)d_ws;
    // persistent weights
    short* o_wt   = (short*)(base + 0);          // 1024x1024
    short* ff1t   = (short*)(base + 2097152);    // 4096x1024
    short* ff2t   = (short*)(base + 10485760);   // 1024x4096
    // phase 1
    short* whb    = (short*)(base + 18874368);   // 5120x3072
    short* rkb    = (short*)(base + 50331648);   // 2560x1024
    short* qkv_wt = (short*)(base + 55574528);   // 3072x1024  [dead after G1]
    short* catb   = (short*)(base + 61865984);   // 5120x1024  [dead after G1]
    short* posb   = (short*)(base + 72351744);   // 2560x1024  [dead after G2]
    short* r_wt   = (short*)(base + 77594624);   // 1024x1024  [dead after G2]
    // phase 2 overlays (over dead prep temps)
    short* vtb    = (short*)(base + 55574528);   // 2x16x64x2560
    short* po     = (short*)(base + 66060288);   // 2x512x64x64
    float* mlb    = (float*)(base + 74448896);   // 2x512x64x2
    short* avb    = (short*)(base + 74973184);   // 2048x1024
    // phase 3 overlays (over dead whb/rkb/vtb/po)
    float* hp0    = (float*)(base + 18874368);   // 2048x1024 f32 partial
    float* hp1    = (float*)(base + 27262976);   // 2048x1024 f32 partial
    float* ares   = (float*)(base + 35651584);   // 2048x1024 f32
    short* aresb  = (short*)(base + 44040192);   // 2048x1024
    short* h1b    = (short*)(base + 48234496);   // 2048x4096

    const dim3 thr(256);

    // 0) all conversions/transposes in one launch
    prep_all<<<dim3(7168), thr, 0, stream>>>(
        mem, c_mem, input_ids, catb, pos_emb, posb,
        qkv_w, qkv_wt, r_w, r_wt, o_w, o_wt, ff_w1, ff1t, ff_w2, ff2t);
    // 1+2) w_heads + r_k in one launch
    gemm_g12<<<dim3(1120), thr, 0, stream>>>(catb, qkv_wt, whb, posb, r_wt, rkb);
    // 3) V^T materialization
    vt_conv<<<dim3(40, 32), thr, 0, stream>>>(whb, vtb);
    // 4) split-K flash attention (XCD-swizzled 1D launch) + merge
    attn_mfma<<<dim3(1024), thr, 0, stream>>>(
        whb, vtb, rkb, r_w_bias, r_r_bias, po, mlb);
    attn_merge<<<dim3(512), thr, 0, stream>>>(po, mlb, avb);
    // 5) attn_out = avb @ o_w, split-K 2x (K=1024 -> 512)
    gemm_split<<<dim3(8, 16, 2), thr, 0, stream>>>(
        avb, o_wt, hp0, hp1, 1024, 1024, 512);
    // 6) attn_res = LN(input + hp0 + hp1)
    ln_fuse<true, false><<<dim3(2048), thr, 0, stream>>>(
        hp0, hp1, nullptr, input_ids, ln_a_s, ln_a_b, ares, aresb);
    // 7) h1 = relu(ares @ ff_w1 + b1)
    gemm_relu<<<dim3(32, 16), thr, 0, stream>>>(aresb, ff1t, ff_b1, h1b, 4096, 1024);
    // 8) h2-partials = h1 @ ff_w2, split-K 2x (K=4096 -> 2048)
    gemm_split<<<dim3(8, 16, 2), thr, 0, stream>>>(
        h1b, ff2t, hp0, hp1, 1024, 4096, 2048);
    // 9) out = LN(ares + hp0 + hp1 + b2)
    ln_fuse<false, true><<<dim3(2048), thr, 0, stream>>>(
        hp0, hp1, ff_b2, ares, ln_f_s, ln_f_b, (float*)d_out, nullptr);
}